// Round 13
// baseline (344.172 us; speedup 1.0000x reference)
//
#include <hip/hip_runtime.h>
#include <stdint.h>

// AWQ 4-bit dequant GEMM: out[M,N] = x[M,K] @ W[N,K]^T + bias
// Path 2 (ws >= X+W): prepass x->fp16 AND W->fp16 into d_ws (pair-permuted,
//   period-4 XOR swizzle baked). GEMM = pure fp16: BM=256 BN=128 BK=32,
//   512 thr (8 waves, 4Mx2N of 64x64), TRIPLE-buffered 72 KB LDS -> 2
//   blocks/CU (4 waves/SIMD: cross-block overlap hides barrier/latency),
//   stage t+2, tile-end s_waitcnt vmcnt(3) counted + s_barrier.
// Path 1 (ws >= X): R11 kernel. Path 0: reg-staged fallback.

#define BM 256
#define BN 256   // path-1 tiles (unchanged)

typedef _Float16 f16x2 __attribute__((ext_vector_type(2)));
typedef _Float16 f16x8 __attribute__((ext_vector_type(8)));
typedef float f32x4 __attribute__((ext_vector_type(4)));
typedef unsigned int u32x4 __attribute__((ext_vector_type(4)));

// ---------- prepass (path 2): x -> fp16, pair-perm, period-4 swizzle ----------
__global__ void convert_x2_kernel(const float* __restrict__ x,
                                  unsigned short* __restrict__ xh,
                                  int M, int K) {
    int g = blockIdx.x * blockDim.x + threadIdx.x;
    int kc = K >> 3;
    if (g >= M * kc) return;
    int r  = g / kc;
    int cc = g - r * kc;
    int csrc = (cc & ~3) | ((cc & 3) ^ ((r >> 1) & 3));
    const float* p = x + (size_t)r * K + (csrc << 3);
    float4 f0 = *reinterpret_cast<const float4*>(p);
    float4 f1 = *reinterpret_cast<const float4*>(p + 4);
    u32x4 o;
    o.x = __builtin_bit_cast(uint32_t, __builtin_amdgcn_cvt_pkrtz(f0.x, f1.x));
    o.y = __builtin_bit_cast(uint32_t, __builtin_amdgcn_cvt_pkrtz(f0.y, f1.y));
    o.z = __builtin_bit_cast(uint32_t, __builtin_amdgcn_cvt_pkrtz(f0.z, f1.z));
    o.w = __builtin_bit_cast(uint32_t, __builtin_amdgcn_cvt_pkrtz(f0.w, f1.w));
    u32x4* dst = reinterpret_cast<u32x4*>(xh + (size_t)r * K + (cc << 3));
    __builtin_nontemporal_store(o, dst);
}

// ---------- prepass (path 2): W (int4) -> fp16 dequant, pair-perm, swizzle ----
__global__ void convert_w2_kernel(const int* __restrict__ qw,
                                  const int* __restrict__ qz,
                                  const float* __restrict__ sc,
                                  unsigned short* __restrict__ wh,
                                  int Nrows, int K) {
    int g = blockIdx.x * blockDim.x + threadIdx.x;
    int kc = K >> 3;
    if (g >= Nrows * kc) return;
    int o  = g / kc;
    int cc = g - o * kc;
    int ngrp = K >> 7, nzw = ngrp >> 3;
    int grp = cc >> 4;
    float s = sc[(size_t)o * ngrp + grp];
    uint32_t z = ((uint32_t)qz[(size_t)o * nzw + (grp >> 3)] >> ((grp & 7) << 2)) & 0xF;
    uint32_t u = (uint32_t)qw[(size_t)o * kc + cc];
    _Float16 hs = (_Float16)s;
    _Float16 hz = (_Float16)(1024.0f + (float)z);
    f16x2 s2 = {hs, hs}, z2 = {hz, hz};
    const uint32_t MK = 0x000F000Fu, MG = 0x64006400u;
    uint32_t p0 = (u & MK) | MG;
    uint32_t p1 = ((u >> 4) & MK) | MG;
    uint32_t p2 = ((u >> 8) & MK) | MG;
    uint32_t p3 = ((u >> 12) & MK) | MG;
    u32x4 ov;
    ov.x = __builtin_bit_cast(uint32_t, (__builtin_bit_cast(f16x2, p0) - z2) * s2);
    ov.y = __builtin_bit_cast(uint32_t, (__builtin_bit_cast(f16x2, p1) - z2) * s2);
    ov.z = __builtin_bit_cast(uint32_t, (__builtin_bit_cast(f16x2, p2) - z2) * s2);
    ov.w = __builtin_bit_cast(uint32_t, (__builtin_bit_cast(f16x2, p3) - z2) * s2);
    int cdst = (cc & ~3) | ((cc & 3) ^ ((o >> 1) & 3));
    u32x4* dst = reinterpret_cast<u32x4*>(wh + (size_t)o * K + (cdst << 3));
    __builtin_nontemporal_store(ov, dst);
}

// ---------- path 2 GEMM: pure fp16, BM=256 BN=128 BK=32, 2 blocks/CU --------
__global__ __launch_bounds__(512, 4) void awq_gemm2_kernel(
    const unsigned short* __restrict__ xh,
    const unsigned short* __restrict__ wh,
    const float* __restrict__ bias,
    float* __restrict__ out,
    int M, int N, int K)
{
    extern __shared__ __align__(16) unsigned short lds[];
    const int ATSZ = 256 * 32;                // 8192 u16 (16 KB)
    const int BTSZ = 128 * 32;                // 4096 u16 (8 KB)
    unsigned short* As = lds;                 // [3][ATSZ]
    unsigned short* Bs = lds + 3 * ATSZ;      // [3][BTSZ]

    const int tid  = threadIdx.x;
    const int lane = tid & 63;
    const int wave = tid >> 6;
    const int wr   = wave & 3;                // 64-row quarter of 256
    const int wc   = wave >> 2;               // 64-col half of 128
    const int lrow = lane & 15;
    const int cswz = (((lane >> 4) ^ ((lrow >> 1) & 3)) << 3);

    const int cpx = gridDim.x >> 3;
    const int bid = (blockIdx.x & 7) * cpx + (blockIdx.x >> 3);
    const int ntn = N / 128;                  // 32
    const int m0 = (bid / ntn) * 256;
    const int n0 = (bid % ntn) * 128;
    const int NT = K / 32;

    f32x4 acc[4][4];
    #pragma unroll
    for (int m = 0; m < 4; ++m)
        #pragma unroll
        for (int n = 0; n < 4; ++n)
            #pragma unroll
            for (int e = 0; e < 4; ++e) acc[m][n][e] = 0.f;

    // A: 2 glds/wave (16 rows each); B: 1 glds/wave (16 rows)
    auto GLDSA = [&](int kt, unsigned short* dst) {
        #pragma unroll
        for (int i = 0; i < 2; ++i) {
            int row = wave * 32 + i * 16 + (lane >> 2);
            const unsigned short* g = xh + (size_t)(m0 + row) * K + kt + ((lane & 3) << 3);
            unsigned short* d = dst + row * 32 + ((lane & 3) << 3);
            __builtin_amdgcn_global_load_lds(
                (const __attribute__((address_space(1))) unsigned int*)g,
                (__attribute__((address_space(3))) unsigned int*)d, 16, 0, 0);
        }
    };
    auto GLDSB = [&](int kt, unsigned short* dst) {
        int row = wave * 16 + (lane >> 2);
        const unsigned short* g = wh + (size_t)(n0 + row) * K + kt + ((lane & 3) << 3);
        unsigned short* d = dst + row * 32 + ((lane & 3) << 3);
        __builtin_amdgcn_global_load_lds(
            (const __attribute__((address_space(1))) unsigned int*)g,
            (__attribute__((address_space(3))) unsigned int*)d, 16, 0, 0);
    };

    // ---- prologue: stage tiles 0,1 into buf 0,1; full drain; barrier
    GLDSA(0, As);
    GLDSB(0, Bs);
    if (NT > 1) {
        GLDSA(32, As + ATSZ);
        GLDSB(32, Bs + BTSZ);
    }
    asm volatile("s_waitcnt vmcnt(0)" ::: "memory");
    __syncthreads();

    for (int t = 0; t < NT; ++t) {
        const int buf = t % 3;
        const unsigned short* Ab = As + buf * ATSZ;
        const unsigned short* Bb = Bs + buf * BTSZ;
        const bool deep = (t + 2 < NT);
        if (deep) {
            const int sb = (t + 2) % 3;
            GLDSA((t + 2) * 32, As + sb * ATSZ);
            GLDSB((t + 2) * 32, Bs + sb * BTSZ);
        }

        f16x8 af[4], bf[4];
        #pragma unroll
        for (int n = 0; n < 4; ++n) {
            int row = wc * 64 + n * 16 + lrow;
            bf[n] = __builtin_bit_cast(f16x8,
                    *reinterpret_cast<const uint4*>(&Bb[row * 32 + cswz]));
        }
        #pragma unroll
        for (int m = 0; m < 4; ++m) {
            int row = wr * 64 + m * 16 + lrow;
            af[m] = __builtin_bit_cast(f16x8,
                    *reinterpret_cast<const uint4*>(&Ab[row * 32 + cswz]));
        }
        #pragma unroll
        for (int m = 0; m < 4; ++m)
            #pragma unroll
            for (int n = 0; n < 4; ++n)
                acc[m][n] = __builtin_amdgcn_mfma_f32_16x16x32_f16(
                    af[m], bf[n], acc[m][n], 0, 0, 0);

        // counted: leave t+2's 3 glds in flight; tail drains 0.
        if (deep) { asm volatile("s_waitcnt vmcnt(3)" ::: "memory"); }
        else      { asm volatile("s_waitcnt vmcnt(0)" ::: "memory"); }
        __builtin_amdgcn_s_barrier();
    }

    // epilogue: C frag col=lane&15, row=(lane>>4)*4+e
    const int r4 = (lane >> 4) << 2;
    #pragma unroll
    for (int n = 0; n < 4; ++n) {
        int col = n0 + wc * 64 + n * 16 + lrow;
        float bv = bias[col];
        #pragma unroll
        for (int m = 0; m < 4; ++m) {
            size_t rbase = (size_t)(m0 + wr * 64 + m * 16 + r4) * N + col;
            #pragma unroll
            for (int e = 0; e < 4; ++e)
                __builtin_nontemporal_store(acc[m][n][e] + bv, &out[rbase + (size_t)e * N]);
        }
    }
}

// ================= path 1 / 0: R11 kernel (unchanged) =======================
#define BK 64

__global__ void convert_x_kernel(const float* __restrict__ x,
                                 unsigned short* __restrict__ xh,
                                 int M, int K) {
    int g = blockIdx.x * blockDim.x + threadIdx.x;
    int kc = K >> 3;
    if (g >= M * kc) return;
    int r  = g / kc;
    int cc = g - r * kc;
    int tile = cc >> 3;
    int cpos = (cc & 7) << 3;
    int sw   = (r & 7) << 3;
    const float* p = x + (size_t)r * K + (tile << 6) + (cpos ^ sw);
    float4 f0 = *reinterpret_cast<const float4*>(p);
    float4 f1 = *reinterpret_cast<const float4*>(p + 4);
    u32x4 o;
    o.x = __builtin_bit_cast(uint32_t, __builtin_amdgcn_cvt_pkrtz(f0.x, f1.x));
    o.y = __builtin_bit_cast(uint32_t, __builtin_amdgcn_cvt_pkrtz(f0.y, f1.y));
    o.z = __builtin_bit_cast(uint32_t, __builtin_amdgcn_cvt_pkrtz(f0.z, f1.z));
    o.w = __builtin_bit_cast(uint32_t, __builtin_amdgcn_cvt_pkrtz(f0.w, f1.w));
    u32x4* dst = reinterpret_cast<u32x4*>(xh + (size_t)r * K + (tile << 6) + cpos);
    __builtin_nontemporal_store(o, dst);
}

template <bool WS>
__global__ __launch_bounds__(512, 2) void awq_gemm_kernel(
    const float* __restrict__ x,
    const unsigned short* __restrict__ xh,
    const int*   __restrict__ qw,
    const int*   __restrict__ qz,
    const float* __restrict__ sc,
    const float* __restrict__ bias,
    float*       __restrict__ out,
    int M, int N, int K)
{
    extern __shared__ __align__(16) unsigned short lds[];
    const int ASZ  = BM * BK;
    const int BPSZ = BN * (BK / 8);
    const int NBUF = WS ? 3 : 2;
    unsigned short* As = lds;
    uint32_t* Bp = reinterpret_cast<uint32_t*>(lds + NBUF * ASZ);

    const int tid  = threadIdx.x;
    const int lane = tid & 63;
    const int wave = tid >> 6;
    const int wr   = wave >> 2;
    const int wc   = wave & 3;
    const int lrow = lane & 15;
    const int lko  = (lane >> 4) << 3;
    const int swr  = (lrow & 7) << 3;

    const int cpx = gridDim.x >> 3;
    const int bid = (blockIdx.x & 7) * cpx + (blockIdx.x >> 3);
    const int ntn = N / BN;
    const int m0 = (bid / ntn) * BM;
    const int n0 = (bid % ntn) * BN;

    const int ngrp = K >> 7;
    const int nzw  = ngrp >> 3;
    const int kw   = K >> 3;
    const int NT   = K / BK;

    const int r_s = tid >> 1;
    const int kh  = tid & 1;
    const int sws = (r_s & 7) << 3;

    f32x4 acc[8][4];
    #pragma unroll
    for (int m = 0; m < 8; ++m)
        #pragma unroll
        for (int n = 0; n < 4; ++n)
            #pragma unroll
            for (int e = 0; e < 4; ++e) acc[m][n][e] = 0.f;

    float    sc_pf[4];
    uint32_t zq_pf[4];
    f16x2    ss[4], zz[4];
    auto PFG = [&](int grp) {
        #pragma unroll
        for (int n = 0; n < 4; ++n) {
            int og = n0 + wc * 64 + n * 16 + lrow;
            sc_pf[n] = sc[(size_t)og * ngrp + grp];
            zq_pf[n] = (uint32_t)qz[(size_t)og * nzw + (grp >> 3)];
        }
    };
    auto SETG = [&](int grp) {
        #pragma unroll
        for (int n = 0; n < 4; ++n) {
            _Float16 s = (_Float16)sc_pf[n];
            uint32_t z = (zq_pf[n] >> ((grp & 7) << 2)) & 0xF;
            _Float16 Z = (_Float16)(float)(1024u + z);
            ss[n][0] = s; ss[n][1] = s;
            zz[n][0] = Z; zz[n][1] = Z;
        }
    };

    float4 a32[8];

    auto GLDSB = [&](int kt, uint32_t* Bw) {
        int row = tid >> 1;
        const int* g = qw + (size_t)(n0 + row) * kw + (kt >> 3) + (tid & 1) * 4;
        uint32_t* d = Bw + row * 8 + (tid & 1) * 4;
        __builtin_amdgcn_global_load_lds(
            (const __attribute__((address_space(1))) unsigned int*)g,
            (__attribute__((address_space(3))) unsigned int*)d, 16, 0, 0);
    };
    auto GLDSA = [&](int kt, unsigned short* Aw) {
        #pragma unroll
        for (int i = 0; i < 4; ++i) {
            int row = wave * 32 + i * 8 + (lane >> 3);
            const unsigned short* g = xh + (size_t)(m0 + row) * K + kt + ((lane & 7) << 3);
            unsigned short* d = Aw + row * BK + ((lane & 7) << 3);
            __builtin_amdgcn_global_load_lds(
                (const __attribute__((address_space(1))) unsigned int*)g,
                (__attribute__((address_space(3))) unsigned int*)d, 16, 0, 0);
        }
    };
    auto LOADA = [&](int kt) {
        const float* p = x + (size_t)(m0 + r_s) * K + kt + kh * 32;
        #pragma unroll
        for (int i = 0; i < 8; ++i)
            a32[i] = *reinterpret_cast<const float4*>(p + 4 * i);
    };
    auto WA = [&](unsigned short* dst, int c) {
        uint4 o;
        o.x = __builtin_bit_cast(uint32_t, __builtin_amdgcn_cvt_pkrtz(a32[2*c].x, a32[2*c+1].x));
        o.y = __builtin_bit_cast(uint32_t, __builtin_amdgcn_cvt_pkrtz(a32[2*c].y, a32[2*c+1].y));
        o.z = __builtin_bit_cast(uint32_t, __builtin_amdgcn_cvt_pkrtz(a32[2*c].z, a32[2*c+1].z));
        o.w = __builtin_bit_cast(uint32_t, __builtin_amdgcn_cvt_pkrtz(a32[2*c].w, a32[2*c+1].w));
        int kcol = kh * 32 + 8 * c;
        *reinterpret_cast<uint4*>(&dst[r_s * BK + (kcol ^ sws)]) = o;
    };

    f16x8 af[4], bfA[4], bfB[4];
    auto RDA = [&](const unsigned short* Ab, int mh, int kk) {
        #pragma unroll
        for (int m = 0; m < 4; ++m) {
            int arow = wr * 128 + (mh * 4 + m) * 16 + lrow;
            int idx = arow * BK + ((kk * 32 + lko) ^ swr);
            af[m] = __builtin_bit_cast(f16x8, *reinterpret_cast<const uint4*>(&Ab[idx]));
        }
    };
    auto DEQB = [&](const uint32_t* Bpb, f16x8* b, int kk) {
        const int dcol = kk * 4 + (lane >> 4);
        const uint32_t MK = 0x000F000Fu, MG = 0x64006400u;
        #pragma unroll
        for (int n = 0; n < 4; ++n) {
            int brow = wc * 64 + n * 16 + lrow;
            uint32_t u = Bpb[brow * 8 + dcol];
            uint32_t p0 = (u & MK) | MG;
            uint32_t p1 = ((u >> 4) & MK) | MG;
            uint32_t p2 = ((u >> 8) & MK) | MG;
            uint32_t p3 = ((u >> 12) & MK) | MG;
            u32x4 o;
            o.x = __builtin_bit_cast(uint32_t, (__builtin_bit_cast(f16x2, p0) - zz[n]) * ss[n]);
            o.y = __builtin_bit_cast(uint32_t, (__builtin_bit_cast(f16x2, p1) - zz[n]) * ss[n]);
            o.z = __builtin_bit_cast(uint32_t, (__builtin_bit_cast(f16x2, p2) - zz[n]) * ss[n]);
            o.w = __builtin_bit_cast(uint32_t, (__builtin_bit_cast(f16x2, p3) - zz[n]) * ss[n]);
            b[n] = __builtin_bit_cast(f16x8, o);
        }
    };
    auto MFMAQ = [&](f16x8* bf, int mh) {
        #pragma unroll
        for (int m_ = 0; m_ < 4; ++m_)
            #pragma unroll
            for (int n_ = 0; n_ < 4; ++n_)
                acc[mh * 4 + m_][n_] = __builtin_amdgcn_mfma_f32_16x16x32_f16(
                    af[m_], bf[n_], acc[mh * 4 + m_][n_], 0, 0, 0);
    };

    PFG(0);
    if constexpr (WS) {
        GLDSB(0, Bp);
        GLDSA(0, As);
        if (NT > 1) { GLDSB(BK, Bp + BPSZ); GLDSA(BK, As + ASZ); }
        asm volatile("s_waitcnt vmcnt(0)" ::: "memory");
        SETG(0);
        __syncthreads();
    } else {
        GLDSB(0, Bp);
        LOADA(0);
        asm volatile("s_waitcnt vmcnt(0)" ::: "memory");
        #pragma unroll
        for (int c = 0; c < 4; ++c) WA(As, c);
        SETG(0);
        __syncthreads();
    }

    for (int t = 0; t < NT; ++t) {
        const int grp = t >> 1;
        if (t && !(t & 1)) SETG(grp);
        if ((t & 1) && grp + 1 < ngrp) PFG(grp + 1);

        const unsigned short* Ab;
        const uint32_t* Bpb;
        if constexpr (WS) {
            const int buf = t % 3;
            Ab = As + buf * ASZ;
            Bpb = Bp + buf * BPSZ;
            if (t + 2 < NT) {
                const int sb = (t + 2) % 3;
                GLDSB((t + 2) * BK, Bp + sb * BPSZ);
                GLDSA((t + 2) * BK, As + sb * ASZ);
            }
        } else {
            const int buf = t & 1;
            Ab = As + buf * ASZ;
            Bpb = Bp + buf * BPSZ;
            if (t + 1 < NT) {
                GLDSB((t + 1) * BK, Bp + (buf ^ 1) * BPSZ);
                LOADA((t + 1) * BK);
            }
        }

        DEQB(Bpb, bfA, 0);
        RDA(Ab, 0, 0);
        MFMAQ(bfA, 0);
        RDA(Ab, 1, 0);
        MFMAQ(bfA, 1);
        DEQB(Bpb, bfB, 1);
        RDA(Ab, 0, 1);
        MFMAQ(bfB, 0);
        RDA(Ab, 1, 1);
        MFMAQ(bfB, 1);

        if constexpr (WS) {
            if (t + 2 < NT) { asm volatile("s_waitcnt vmcnt(5)" ::: "memory"); }
            else            { asm volatile("s_waitcnt vmcnt(0)" ::: "memory"); }
            __builtin_amdgcn_s_barrier();
        } else {
            if (t + 1 < NT) { WA(As + ((t & 1) ^ 1) * ASZ, 0); WA(As + ((t & 1) ^ 1) * ASZ, 1);
                              WA(As + ((t & 1) ^ 1) * ASZ, 2); WA(As + ((t & 1) ^ 1) * ASZ, 3); }
            __syncthreads();
        }
    }

    const int r4 = (lane >> 4) << 2;
    #pragma unroll
    for (int n = 0; n < 4; ++n) {
        int col = n0 + wc * 64 + n * 16 + lrow;
        float bv = bias[col];
        #pragma unroll
        for (int m = 0; m < 8; ++m) {
            size_t rbase = (size_t)(m0 + wr * 128 + m * 16 + r4) * N + col;
            #pragma unroll
            for (int e = 0; e < 4; ++e)
                __builtin_nontemporal_store(acc[m][n][e] + bv, &out[rbase + (size_t)e * N]);
        }
    }
}

extern "C" void kernel_launch(void* const* d_in, const int* in_sizes, int n_in,
                              void* d_out, int out_size, void* d_ws, size_t ws_size,
                              hipStream_t stream) {
    const float* x   = (const float*)d_in[0];
    const int*   qwp = (const int*)d_in[1];
    const int*   qzp = (const int*)d_in[2];
    const float* scp = (const float*)d_in[3];
    const float* bp  = (const float*)d_in[4];
    float* outp = (float*)d_out;

    const int N = in_sizes[4];                 // 4096 (O)
    const int K = (in_sizes[1] / N) * 8;       // 4096 (I)
    const int M = in_sizes[0] / K;             // 8192 (B)

    dim3 block(512);

    const size_t needX = (size_t)M * K * 2;
    const size_t needW = (size_t)N * K * 2;

    if (ws_size >= needX + needW) {
        // ---- path 2: both operands pre-converted, pure fp16 GEMM, 2 blk/CU
        unsigned short* xh = (unsigned short*)d_ws;
        unsigned short* wh = xh + (size_t)M * K;
        int ncx = M * (K / 8), ncw = N * (K / 8);
        convert_x2_kernel<<<dim3((ncx + 255) / 256), dim3(256), 0, stream>>>(x, xh, M, K);
        convert_w2_kernel<<<dim3((ncw + 255) / 256), dim3(256), 0, stream>>>(qwp, qzp, scp, wh, N, K);
        dim3 grid2((M / 256) * (N / 128));     // 32*32 = 1024
        const int ldsbytes = 3 * (256 * 32 + 128 * 32) * 2;   // 72 KB
        (void)hipFuncSetAttribute(
            reinterpret_cast<const void*>(&awq_gemm2_kernel),
            hipFuncAttributeMaxDynamicSharedMemorySize, ldsbytes);
        awq_gemm2_kernel<<<grid2, block, ldsbytes, stream>>>(xh, wh, bp, outp, M, N, K);
    } else if (ws_size >= needX) {
        unsigned short* xh = (unsigned short*)d_ws;
        int nchunk = M * (K / 8);
        convert_x_kernel<<<dim3((nchunk + 255) / 256), dim3(256), 0, stream>>>(x, xh, M, K);
        dim3 grid((M / BM) * (N / BN));
        const int ldsbytes = 3 * BM * BK * 2 + 3 * BN * (BK / 8) * 4;
        (void)hipFuncSetAttribute(
            reinterpret_cast<const void*>(&awq_gemm_kernel<true>),
            hipFuncAttributeMaxDynamicSharedMemorySize, ldsbytes);
        awq_gemm_kernel<true><<<grid, block, ldsbytes, stream>>>(
            x, xh, qwp, qzp, scp, bp, outp, M, N, K);
    } else {
        dim3 grid((M / BM) * (N / BN));
        const int ldsbytes = 2 * BM * BK * 2 + 2 * BN * (BK / 8) * 4;
        (void)hipFuncSetAttribute(
            reinterpret_cast<const void*>(&awq_gemm_kernel<false>),
            hipFuncAttributeMaxDynamicSharedMemorySize, ldsbytes);
        awq_gemm_kernel<false><<<grid, block, ldsbytes, stream>>>(
            x, nullptr, qwp, qzp, scp, bp, outp, M, N, K);
    }
}